// Round 7
// baseline (153.704 us; speedup 1.0000x reference)
//
#include <hip/hip_runtime.h>

// R7: 3-launch restructure. gemm hot loop = exact R3 (measured 24.4us).
// Launch overhead was ~49us of the 73.3us total (6 launches); now 3:
//   pack(+counter reset) -> gemm(+last-block cvec) -> tree(+last-block tail)

#define NN 32767   // n_nodes
#define NL 16384   // n_leaves
#define DD 1024    // D
#define LL 32      // num labels

typedef __attribute__((ext_vector_type(8))) short bf16x8;
typedef __attribute__((ext_vector_type(4))) float f32x4;

__device__ __forceinline__ short f2bf(float f) {
  union { float f; unsigned u; } x; x.f = f;
  unsigned r = x.u + 0x7FFFu + ((x.u >> 16) & 1u);  // RNE
  return (short)(r >> 16);
}

__device__ __forceinline__ bf16x8 cvt8(float4 a, float4 b) {
  bf16x8 r;
  r[0] = f2bf(a.x); r[1] = f2bf(a.y); r[2] = f2bf(a.z); r[3] = f2bf(a.w);
  r[4] = f2bf(b.x); r[5] = f2bf(b.y); r[6] = f2bf(b.z); r[7] = f2bf(b.w);
  return r;
}

__device__ __forceinline__ void gld_lds16(const float* g, float* l) {
  __builtin_amdgcn_global_load_lds(
      (const __attribute__((address_space(1))) void*)g,
      (__attribute__((address_space(3))) void*)l, 16, 0, 0);
}

// Pack W_pred (both K-halves, all 32 output cols) into bf16 MFMA B-fragment
// order: element idx = ((s*64 + lane)*4 + m)*8 + j. Per (s,lane): 64B chunk.
// Also resets the two completion counters (required every call).
__global__ __launch_bounds__(256) void pack_kernel(const float* __restrict__ Wp,
                                                   short* __restrict__ Wpk,
                                                   unsigned* __restrict__ cnt) {
  if (blockIdx.x == 0 && threadIdx.x == 0) { cnt[0] = 0u; cnt[1] = 0u; }
  int idx = blockIdx.x * 256 + threadIdx.x;   // grid 64 -> 16384 threads
  #pragma unroll
  for (int t = 0; t < 4; ++t, idx += 16384) {
    const int j = idx & 7, m = (idx >> 3) & 3, lane = (idx >> 5) & 63, s = idx >> 11;
    const int wrow = (lane & 15) + 16 * (m & 1);
    const int wcol = (m >> 1) * 1024 + s * 32 + (lane >> 4) * 8 + j;
    Wpk[idx] = f2bf(Wp[(size_t)wrow * (2 * DD) + wcol]);
  }
}

// E0 = hidden @ W1^T (stored) + E2 rowsum partials; last block computes cvec.
// Hot loop identical to R3 (24.4us measured).
__global__ __launch_bounds__(256) void gemm_kernel(
    const float* __restrict__ hidden, const short* __restrict__ Wpk,
    const float* __restrict__ bp, float* __restrict__ E0,
    float* __restrict__ gpartB, float* __restrict__ cvec,
    unsigned* __restrict__ cnt) {
  __shared__ float lds[4 * 3 * 1024];           // 4 waves x 3 bufs x 4KB
  __shared__ float part2[4][LL];
  __shared__ float partC[8][LL];
  __shared__ bool amLast;
  const int tid = threadIdx.x;
  const int wid = tid >> 6, lane = tid & 63;
  const int tile = blockIdx.x * 4 + wid;        // 0..2047, 16 rows each
  const int mrow = lane & 15, g = lane >> 4;
  const int swz = (mrow & 7) << 4;              // byte XOR for ds_read side
  float* ldsw = lds + wid * 3072;

  const float* ab0; const float* ab1; const float* ab2; const float* ab3;
  {
    const int lr = lane >> 4, lc16 = (lane & 15) * 16;
    #define MKAB(I, P) { const int row = (I)*4 + lr;                         \
      const int csrc = lc16 ^ ((row & 7) << 4);                              \
      int grow = tile * 16 + row; if (grow > NN - 1) grow = NN - 1;          \
      P = hidden + (size_t)grow * DD + (csrc >> 2); }
    MKAB(0, ab0) MKAB(1, ab1) MKAB(2, ab2) MKAB(3, ab3)
    #undef MKAB
  }
  const bf16x8* wbase = (const bf16x8*)Wpk + (size_t)lane * 4;

  const int cidx00 = ((g * 32) ^ swz) >> 2;
  const int cidx01 = ((g * 32 + 16) ^ swz) >> 2;
  const int cidx10 = ((128 + g * 32) ^ swz) >> 2;
  const int cidx11 = ((128 + g * 32 + 16) ^ swz) >> 2;

  f32x4 acc0 = {0,0,0,0}, acc1 = {0,0,0,0}, acc2 = {0,0,0,0}, acc3 = {0,0,0,0};

#define STAGE_A(KC) {                                   \
    float* ld_ = ldsw + ((KC) % 3) * 1024;              \
    gld_lds16(ab0 + (KC) * 64, ld_);                    \
    gld_lds16(ab1 + (KC) * 64, ld_ + 256);              \
    gld_lds16(ab2 + (KC) * 64, ld_ + 512);              \
    gld_lds16(ab3 + (KC) * 64, ld_ + 768); }

#define LOAD_W(KC, W0,W1,W2,W3, X0,X1,X2,X3) {          \
    const bf16x8* p_ = wbase + (size_t)(2 * (KC)) * 256; \
    W0 = p_[0];   W1 = p_[1];   W2 = p_[2];   W3 = p_[3]; \
    X0 = p_[256]; X1 = p_[257]; X2 = p_[258]; X3 = p_[259]; }

#define CHUNK(KC, VM, W0,W1,W2,W3, X0,X1,X2,X3)                              \
  { if ((KC) + 2 < 16) STAGE_A((KC) + 2)                                     \
    asm volatile("s_waitcnt vmcnt(" VM ")" ::: "memory");                    \
    { const float* bc = ldsw + ((KC) % 3) * 1024 + mrow * 64;                \
      float4 fa0 = *(const float4*)(bc + cidx00);                            \
      float4 fb0 = *(const float4*)(bc + cidx01);                            \
      bf16x8 af0 = cvt8(fa0, fb0);                                           \
      acc0 = __builtin_amdgcn_mfma_f32_16x16x32_bf16(af0, W0, acc0, 0,0,0);  \
      acc1 = __builtin_amdgcn_mfma_f32_16x16x32_bf16(af0, W1, acc1, 0,0,0);  \
      acc2 = __builtin_amdgcn_mfma_f32_16x16x32_bf16(af0, W2, acc2, 0,0,0);  \
      acc3 = __builtin_amdgcn_mfma_f32_16x16x32_bf16(af0, W3, acc3, 0,0,0);  \
      float4 fa1 = *(const float4*)(bc + cidx10);                            \
      float4 fb1 = *(const float4*)(bc + cidx11);                            \
      bf16x8 af1 = cvt8(fa1, fb1);                                           \
      acc0 = __builtin_amdgcn_mfma_f32_16x16x32_bf16(af1, X0, acc0, 0,0,0);  \
      acc1 = __builtin_amdgcn_mfma_f32_16x16x32_bf16(af1, X1, acc1, 0,0,0);  \
      acc2 = __builtin_amdgcn_mfma_f32_16x16x32_bf16(af1, X2, acc2, 0,0,0);  \
      acc3 = __builtin_amdgcn_mfma_f32_16x16x32_bf16(af1, X3, acc3, 0,0,0);  \
    }                                                                        \
    if ((KC) + 2 < 16) LOAD_W((KC) + 2, W0,W1,W2,W3, X0,X1,X2,X3) }

  bf16x8 u0,u1,u2,u3,u4,u5,u6,u7, v0,v1,v2,v3,v4,v5,v6,v7;
  STAGE_A(0) STAGE_A(1)
  LOAD_W(0, u0,u1,u2,u3, u4,u5,u6,u7)
  LOAD_W(1, v0,v1,v2,v3, v4,v5,v6,v7)
  CHUNK( 0, "24", u0,u1,u2,u3, u4,u5,u6,u7)
  CHUNK( 1, "32", v0,v1,v2,v3, v4,v5,v6,v7)
  CHUNK( 2, "24", u0,u1,u2,u3, u4,u5,u6,u7)
  CHUNK( 3, "24", v0,v1,v2,v3, v4,v5,v6,v7)
  CHUNK( 4, "24", u0,u1,u2,u3, u4,u5,u6,u7)
  CHUNK( 5, "24", v0,v1,v2,v3, v4,v5,v6,v7)
  CHUNK( 6, "24", u0,u1,u2,u3, u4,u5,u6,u7)
  CHUNK( 7, "24", v0,v1,v2,v3, v4,v5,v6,v7)
  CHUNK( 8, "24", u0,u1,u2,u3, u4,u5,u6,u7)
  CHUNK( 9, "24", v0,v1,v2,v3, v4,v5,v6,v7)
  CHUNK(10, "24", u0,u1,u2,u3, u4,u5,u6,u7)
  CHUNK(11, "24", v0,v1,v2,v3, v4,v5,v6,v7)
  CHUNK(12, "24", u0,u1,u2,u3, u4,u5,u6,u7)
  CHUNK(13, "24", v0,v1,v2,v3, v4,v5,v6,v7)
  CHUNK(14, "20", u0,u1,u2,u3, u4,u5,u6,u7)
  CHUNK(15, "8",  v0,v1,v2,v3, v4,v5,v6,v7)
#undef CHUNK
#undef LOAD_W
#undef STAGE_A

  // E0 store: D layout col=lane&15, row=(lane>>4)*4+r
  #pragma unroll
  for (int r = 0; r < 4; ++r) {
    const int srow = tile * 16 + g * 4 + r;
    if (srow < NN) {
      E0[(size_t)srow * LL + mrow]      = acc0[r];
      E0[(size_t)srow * LL + mrow + 16] = acc1[r];
    }
  }
  // E2 rowsum partial (drop duplicated clamped row in last tile)
  if (tile == 2047 && g == 3) { acc2[3] = 0.f; acc3[3] = 0.f; }
  float s2 = acc2[0] + acc2[1] + acc2[2] + acc2[3];
  float s3 = acc3[0] + acc3[1] + acc3[2] + acc3[3];
  s2 += __shfl_xor(s2, 16, 64); s2 += __shfl_xor(s2, 32, 64);
  s3 += __shfl_xor(s3, 16, 64); s3 += __shfl_xor(s3, 32, 64);
  if (lane < 32) part2[wid][lane] = (lane < 16) ? s2 : s3;
  __syncthreads();
  if (tid < LL) {
    gpartB[blockIdx.x * LL + tid] =
        part2[0][tid] + part2[1][tid] + part2[2][tid] + part2[3][tid];
  }
  __syncthreads();
  // last-block-done: the 512th block reduces gpartB -> cvec
  if (tid == 0) {
    __threadfence();
    unsigned old = atomicAdd(&cnt[0], 1u);
    amLast = (old == 511u);
  }
  __syncthreads();
  if (amLast) {
    __threadfence();
    const int col = tid & 31, rg = tid >> 5;   // 8 row-groups
    float s = 0.f;
    for (int r = rg; r < 512; r += 8) s += gpartB[(size_t)r * LL + col];
    partC[rg][col] = s;
    __syncthreads();
    if (tid < LL) {
      float ss = partC[0][tid] + partC[1][tid] + partC[2][tid] + partC[3][tid] +
                 partC[4][tid] + partC[5][tid] + partC[6][tid] + partC[7][tid];
      cvec[tid] = bp[tid] + ss * (1.0f / (float)NN);
    }
  }
}

__device__ __forceinline__ float lse32(const float4* tt, const float4* sv) {
  float m = -3.0e38f;
  float4 v[8];
  #pragma unroll
  for (int i = 0; i < 8; ++i) {
    float4 t = tt[i], s = sv[i], w;
    w.x = t.x + s.x; w.y = t.y + s.y; w.z = t.z + s.z; w.w = t.w + s.w;
    v[i] = w;
    m = fmaxf(m, fmaxf(fmaxf(w.x, w.y), fmaxf(w.z, w.w)));
  }
  float ss = 0.f;
  #pragma unroll
  for (int i = 0; i < 8; ++i) {
    ss += __expf(v[i].x - m) + __expf(v[i].y - m) +
          __expf(v[i].z - m) + __expf(v[i].w - m);
  }
  return m + __logf(ss);
}

// Five tree levels (widths 8192..512); the last-finishing block then runs the
// single-block tail (widths 256..1) in 64KB LDS and writes the root.
__global__ __launch_bounds__(1024) void tree_kernel(
    const float* __restrict__ E0, const float* __restrict__ cvec,
    const float* __restrict__ trans, float* __restrict__ S5,
    float* __restrict__ out, unsigned* __restrict__ cnt) {
  __shared__ float l1[16][LL], l2[8][LL], l3[4][LL];
  __shared__ float ts[511 * LL];               // tail scores (nodes 32256..32766)
  __shared__ bool amLast;
  const int wid = threadIdx.x >> 6, lane = threadIdx.x & 63;
  const int j = lane & 31, half = lane >> 5;
  const int b = blockIdx.x, G = gridDim.x;
  float4 tt[8];
  #pragma unroll
  for (int i = 0; i < 8; ++i) tt[i] = *(const float4*)(trans + j * LL + i * 4);
  const float cj = cvec[j];
  float4 sv[8];
  const int base1 = NL;

  { // phase 1 (leaves as children; add cvec to leaf emissions)
    const int n = b * 16 + wid;
    const float* sp = E0 + (size_t)(2 * n + half) * LL;
    #pragma unroll
    for (int i = 0; i < 8; ++i) {
      float4 vv = *(const float4*)(sp + i * 4);
      float4 c4 = *(const float4*)(cvec + i * 4);
      vv.x += c4.x; vv.y += c4.y; vv.z += c4.z; vv.w += c4.w;
      sv[i] = vv;
    }
    float lsum = lse32(tt, sv);
    float other = __shfl_xor(lsum, 32, 64);
    float o = E0[(size_t)(base1 + n) * LL + j] + cj + lsum + other;
    if (lane < 32) l1[wid][j] = o;
  }
  __syncthreads();
  const int base2 = base1 + G * 16;
  if (wid < 8) {
    const float* sp = l1[2 * wid + half];
    #pragma unroll
    for (int i = 0; i < 8; ++i) sv[i] = *(const float4*)(sp + i * 4);
    float lsum = lse32(tt, sv);
    float other = __shfl_xor(lsum, 32, 64);
    float o = E0[(size_t)(base2 + b * 8 + wid) * LL + j] + cj + lsum + other;
    if (lane < 32) l2[wid][j] = o;
  }
  __syncthreads();
  const int base3 = base2 + G * 8;
  if (wid < 4) {
    const float* sp = l2[2 * wid + half];
    #pragma unroll
    for (int i = 0; i < 8; ++i) sv[i] = *(const float4*)(sp + i * 4);
    float lsum = lse32(tt, sv);
    float other = __shfl_xor(lsum, 32, 64);
    float o = E0[(size_t)(base3 + b * 4 + wid) * LL + j] + cj + lsum + other;
    if (lane < 32) l3[wid][j] = o;
  }
  __syncthreads();
  const int base4 = base3 + G * 4;
  if (wid < 2) {
    const float* sp = l3[2 * wid + half];
    #pragma unroll
    for (int i = 0; i < 8; ++i) sv[i] = *(const float4*)(sp + i * 4);
    float lsum = lse32(tt, sv);
    float other = __shfl_xor(lsum, 32, 64);
    float o = E0[(size_t)(base4 + b * 2 + wid) * LL + j] + cj + lsum + other;
    if (lane < 32) l1[wid][j] = o;
  }
  __syncthreads();
  const int base5 = base4 + G * 2;
  if (wid == 0) {
    const float* sp = l1[half];
    #pragma unroll
    for (int i = 0; i < 8; ++i) sv[i] = *(const float4*)(sp + i * 4);
    float lsum = lse32(tt, sv);
    float other = __shfl_xor(lsum, 32, 64);
    float o = E0[(size_t)(base5 + b) * LL + j] + cj + lsum + other;
    if (lane < 32) S5[(size_t)b * LL + j] = o;
  }
  __syncthreads();
  // last-block-done: run the tail (widths 256..1)
  if (threadIdx.x == 0) {
    __threadfence();
    unsigned old = atomicAdd(&cnt[1], 1u);
    amLast = (old == 511u);
  }
  __syncthreads();
  if (!amLast) return;
  __threadfence();

  int width = 256, pnode = 32256, cIdxBase = -1;
  while (width >= 1) {
    for (int n = wid; n < width; n += 16) {
      const float* sp = (cIdxBase < 0)
          ? (S5 + (size_t)(2 * n + half) * LL)
          : (ts + (size_t)(cIdxBase + 2 * n + half) * LL);
      #pragma unroll
      for (int i = 0; i < 8; ++i) sv[i] = *(const float4*)(sp + i * 4);
      float lsum = lse32(tt, sv);
      float other = __shfl_xor(lsum, 32, 64);
      if (lane < 32) {
        const int node = pnode + n;
        float o = E0[(size_t)node * LL + j] + cj + lsum + other;
        ts[(size_t)(node - 32256) * LL + j] = o;
        if (node == NN - 1) out[j] = o;
      }
    }
    __syncthreads();
    cIdxBase = pnode - 32256;
    pnode += width;
    width >>= 1;
  }
}

extern "C" void kernel_launch(void* const* d_in, const int* in_sizes, int n_in,
                              void* d_out, int out_size, void* d_ws, size_t ws_size,
                              hipStream_t stream) {
  const float* hidden = (const float*)d_in[0];
  const float* trans  = (const float*)d_in[1];
  const float* Wp     = (const float*)d_in[2];
  const float* bp     = (const float*)d_in[3];

  float* ws     = (float*)d_ws;
  float* E0     = ws;                               // NN*32 f32
  float* gpartB = E0 + (size_t)NN * LL;             // 512*32 f32
  float* cvecb  = gpartB + 512 * LL;                // 32 f32
  float* S5     = cvecb + 32;                       // 512*32 f32
  short* Wpk    = (short*)(S5 + 512 * LL);          // 65536 bf16
  unsigned* cnt = (unsigned*)(Wpk + 65536);         // 2 counters

  pack_kernel<<<64, 256, 0, stream>>>(Wp, Wpk, cnt);
  gemm_kernel<<<512, 256, 0, stream>>>(hidden, Wpk, bp, E0, gpartB, cvecb, cnt);
  tree_kernel<<<512, 1024, 0, stream>>>(E0, cvecb, trans, S5, (float*)d_out, cnt);
}

// Round 8
// 89.880 us; speedup vs baseline: 1.7101x; 1.7101x over previous
//
#include <hip/hip_runtime.h>

// R8: revert to R3's proven pack+gemm (byte-identical hot loop), restructure
// the rest: 6 launches -> 4, NO device fences (R7's __threadfence = L2
// writeback x512 = 4x gemm poison).
//   pack -> gemm -> treeA(256 blocks, widths 8192..256, +cvec) ->
//   tail(1 block, widths 128..1, +cvec)

#define NN 32767   // n_nodes
#define NL 16384   // n_leaves
#define DD 1024    // D
#define LL 32      // num labels

typedef __attribute__((ext_vector_type(8))) short bf16x8;
typedef __attribute__((ext_vector_type(4))) float f32x4;

__device__ __forceinline__ short f2bf(float f) {
  union { float f; unsigned u; } x; x.f = f;
  unsigned r = x.u + 0x7FFFu + ((x.u >> 16) & 1u);  // RNE
  return (short)(r >> 16);
}

__device__ __forceinline__ bf16x8 cvt8(float4 a, float4 b) {
  bf16x8 r;
  r[0] = f2bf(a.x); r[1] = f2bf(a.y); r[2] = f2bf(a.z); r[3] = f2bf(a.w);
  r[4] = f2bf(b.x); r[5] = f2bf(b.y); r[6] = f2bf(b.z); r[7] = f2bf(b.w);
  return r;
}

__device__ __forceinline__ void gld_lds16(const float* g, float* l) {
  __builtin_amdgcn_global_load_lds(
      (const __attribute__((address_space(1))) void*)g,
      (__attribute__((address_space(3))) void*)l, 16, 0, 0);
}

// Pack W_pred (both K-halves, all 32 output cols) into bf16 MFMA B-fragment
// order: element idx = ((s*64 + lane)*4 + m)*8 + j. Per (s,lane): 64B chunk.
__global__ __launch_bounds__(256) void pack_kernel(const float* __restrict__ Wp,
                                                   short* __restrict__ Wpk) {
  int idx = blockIdx.x * 256 + threadIdx.x;   // grid 64 -> 16384 threads
  #pragma unroll
  for (int t = 0; t < 4; ++t, idx += 16384) {
    const int j = idx & 7, m = (idx >> 3) & 3, lane = (idx >> 5) & 63, s = idx >> 11;
    const int wrow = (lane & 15) + 16 * (m & 1);
    const int wcol = (m >> 1) * 1024 + s * 32 + (lane >> 4) * 8 + j;
    Wpk[idx] = f2bf(Wp[(size_t)wrow * (2 * DD) + wcol]);
  }
}

// E0 = hidden @ W1^T (stored) + rowsum partials of E2 = hidden @ W2^T (gpart).
// Barrier-free per-wave global_load_lds pipeline, depth-2, triple LDS buffer,
// XOR-swizzled (source-side + read-side). EXACT R3 code - do not touch.
__global__ __launch_bounds__(256) void gemm_kernel(
    const float* __restrict__ hidden, const short* __restrict__ Wpk,
    float* __restrict__ E0, float* __restrict__ gpart) {
  __shared__ float lds[4 * 3 * 1024];           // 4 waves x 3 bufs x 4KB
  const int tid = threadIdx.x;
  const int wid = tid >> 6, lane = tid & 63;
  const int tile = blockIdx.x * 4 + wid;        // 0..2047, 16 rows each
  const int mrow = lane & 15, g = lane >> 4;
  const int swz = (mrow & 7) << 4;              // byte XOR for ds_read side
  float* ldsw = lds + wid * 3072;

  // Per-lane staging base pointers (4 rows per wave-iteration).
  const float* ab0; const float* ab1; const float* ab2; const float* ab3;
  {
    const int lr = lane >> 4, lc16 = (lane & 15) * 16;
    #define MKAB(I, P) { const int row = (I)*4 + lr;                         \
      const int csrc = lc16 ^ ((row & 7) << 4);                              \
      int grow = tile * 16 + row; if (grow > NN - 1) grow = NN - 1;          \
      P = hidden + (size_t)grow * DD + (csrc >> 2); }
    MKAB(0, ab0) MKAB(1, ab1) MKAB(2, ab2) MKAB(3, ab3)
    #undef MKAB
  }
  const bf16x8* wbase = (const bf16x8*)Wpk + (size_t)lane * 4;

  const int cidx00 = ((g * 32) ^ swz) >> 2;
  const int cidx01 = ((g * 32 + 16) ^ swz) >> 2;
  const int cidx10 = ((128 + g * 32) ^ swz) >> 2;
  const int cidx11 = ((128 + g * 32 + 16) ^ swz) >> 2;

  f32x4 acc0 = {0,0,0,0}, acc1 = {0,0,0,0}, acc2 = {0,0,0,0}, acc3 = {0,0,0,0};

#define STAGE_A(KC) {                                   \
    float* ld_ = ldsw + ((KC) % 3) * 1024;              \
    gld_lds16(ab0 + (KC) * 64, ld_);                    \
    gld_lds16(ab1 + (KC) * 64, ld_ + 256);              \
    gld_lds16(ab2 + (KC) * 64, ld_ + 512);              \
    gld_lds16(ab3 + (KC) * 64, ld_ + 768); }

#define LOAD_W(KC, W0,W1,W2,W3, X0,X1,X2,X3) {          \
    const bf16x8* p_ = wbase + (size_t)(2 * (KC)) * 256; \
    W0 = p_[0];   W1 = p_[1];   W2 = p_[2];   W3 = p_[3]; \
    X0 = p_[256]; X1 = p_[257]; X2 = p_[258]; X3 = p_[259]; }

#define CHUNK(KC, VM, W0,W1,W2,W3, X0,X1,X2,X3)                              \
  { if ((KC) + 2 < 16) STAGE_A((KC) + 2)                                     \
    asm volatile("s_waitcnt vmcnt(" VM ")" ::: "memory");                    \
    { const float* bc = ldsw + ((KC) % 3) * 1024 + mrow * 64;                \
      float4 fa0 = *(const float4*)(bc + cidx00);                            \
      float4 fb0 = *(const float4*)(bc + cidx01);                            \
      bf16x8 af0 = cvt8(fa0, fb0);                                           \
      acc0 = __builtin_amdgcn_mfma_f32_16x16x32_bf16(af0, W0, acc0, 0,0,0);  \
      acc1 = __builtin_amdgcn_mfma_f32_16x16x32_bf16(af0, W1, acc1, 0,0,0);  \
      acc2 = __builtin_amdgcn_mfma_f32_16x16x32_bf16(af0, W2, acc2, 0,0,0);  \
      acc3 = __builtin_amdgcn_mfma_f32_16x16x32_bf16(af0, W3, acc3, 0,0,0);  \
      float4 fa1 = *(const float4*)(bc + cidx10);                            \
      float4 fb1 = *(const float4*)(bc + cidx11);                            \
      bf16x8 af1 = cvt8(fa1, fb1);                                           \
      acc0 = __builtin_amdgcn_mfma_f32_16x16x32_bf16(af1, X0, acc0, 0,0,0);  \
      acc1 = __builtin_amdgcn_mfma_f32_16x16x32_bf16(af1, X1, acc1, 0,0,0);  \
      acc2 = __builtin_amdgcn_mfma_f32_16x16x32_bf16(af1, X2, acc2, 0,0,0);  \
      acc3 = __builtin_amdgcn_mfma_f32_16x16x32_bf16(af1, X3, acc3, 0,0,0);  \
    }                                                                        \
    if ((KC) + 2 < 16) LOAD_W((KC) + 2, W0,W1,W2,W3, X0,X1,X2,X3) }

  bf16x8 u0,u1,u2,u3,u4,u5,u6,u7, v0,v1,v2,v3,v4,v5,v6,v7;
  STAGE_A(0) STAGE_A(1)
  LOAD_W(0, u0,u1,u2,u3, u4,u5,u6,u7)
  LOAD_W(1, v0,v1,v2,v3, v4,v5,v6,v7)
  CHUNK( 0, "24", u0,u1,u2,u3, u4,u5,u6,u7)
  CHUNK( 1, "32", v0,v1,v2,v3, v4,v5,v6,v7)
  CHUNK( 2, "24", u0,u1,u2,u3, u4,u5,u6,u7)
  CHUNK( 3, "24", v0,v1,v2,v3, v4,v5,v6,v7)
  CHUNK( 4, "24", u0,u1,u2,u3, u4,u5,u6,u7)
  CHUNK( 5, "24", v0,v1,v2,v3, v4,v5,v6,v7)
  CHUNK( 6, "24", u0,u1,u2,u3, u4,u5,u6,u7)
  CHUNK( 7, "24", v0,v1,v2,v3, v4,v5,v6,v7)
  CHUNK( 8, "24", u0,u1,u2,u3, u4,u5,u6,u7)
  CHUNK( 9, "24", v0,v1,v2,v3, v4,v5,v6,v7)
  CHUNK(10, "24", u0,u1,u2,u3, u4,u5,u6,u7)
  CHUNK(11, "24", v0,v1,v2,v3, v4,v5,v6,v7)
  CHUNK(12, "24", u0,u1,u2,u3, u4,u5,u6,u7)
  CHUNK(13, "24", v0,v1,v2,v3, v4,v5,v6,v7)
  CHUNK(14, "20", u0,u1,u2,u3, u4,u5,u6,u7)
  CHUNK(15, "8",  v0,v1,v2,v3, v4,v5,v6,v7)
#undef CHUNK
#undef LOAD_W
#undef STAGE_A

  // E0 store: D layout col=lane&15, row=(lane>>4)*4+r
  #pragma unroll
  for (int r = 0; r < 4; ++r) {
    const int srow = tile * 16 + g * 4 + r;
    if (srow < NN) {
      E0[(size_t)srow * LL + mrow]      = acc0[r];
      E0[(size_t)srow * LL + mrow + 16] = acc1[r];
    }
  }
  // Last tile duplicates row 32766 in the clamped slot (row 15) - drop it
  // from the E2 rowsum so cvec stays exact.
  if (tile == 2047 && g == 3) { acc2[3] = 0.f; acc3[3] = 0.f; }
  float s2 = acc2[0] + acc2[1] + acc2[2] + acc2[3];
  float s3 = acc3[0] + acc3[1] + acc3[2] + acc3[3];
  s2 += __shfl_xor(s2, 16, 64); s2 += __shfl_xor(s2, 32, 64);
  s3 += __shfl_xor(s3, 16, 64); s3 += __shfl_xor(s3, 32, 64);
  if (lane < 32) gpart[(size_t)tile * LL + lane] = (lane < 16) ? s2 : s3;
}

__device__ __forceinline__ float lse32(const float4* tt, const float4* sv) {
  float m = -3.0e38f;
  float4 v[8];
  #pragma unroll
  for (int i = 0; i < 8; ++i) {
    float4 t = tt[i], s = sv[i], w;
    w.x = t.x + s.x; w.y = t.y + s.y; w.z = t.z + s.z; w.w = t.w + s.w;
    v[i] = w;
    m = fmaxf(m, fmaxf(fmaxf(w.x, w.y), fmaxf(w.z, w.w)));
  }
  float ss = 0.f;
  #pragma unroll
  for (int i = 0; i < 8; ++i) {
    ss += __expf(v[i].x - m) + __expf(v[i].y - m) +
          __expf(v[i].z - m) + __expf(v[i].w - m);
  }
  return m + __logf(ss);
}

// Per-block cvec: cv[j] = b[j] + colsum(gpart[2048][32])/NN. Needs 1024 thr.
// No fence needed: gpart was written by the previous kernel (launch boundary).
__device__ __forceinline__ void compute_cvec(const float* __restrict__ gpart,
                                             const float* __restrict__ bp,
                                             float* cv, float (*pr)[LL]) {
  const int tid = threadIdx.x;
  const int j = tid & 31, r = tid >> 5;   // r: 0..31
  float s = 0.f;
  #pragma unroll 8
  for (int q = 0; q < 64; ++q) s += gpart[(size_t)(r + q * 32) * LL + j];
  pr[r][j] = s;
  __syncthreads();
  if (tid < LL) {
    float ss = 0.f;
    #pragma unroll
    for (int q = 0; q < 32; ++q) ss += pr[q][tid];
    cv[tid] = bp[tid] + ss * (1.0f / (float)NN);
  }
  __syncthreads();
}

// Six tree levels, widths 8192..256. 256 blocks (one full-chip round), each
// block owns 32 width-8192 nodes and the subtree above them. Output: S[b] =
// scores of width-256 node (32256+b). Children of base_l+n: base_{l-1}+2n,+1.
__global__ __launch_bounds__(1024) void treeA_kernel(
    const float* __restrict__ E0, const float* __restrict__ gpart,
    const float* __restrict__ bp, const float* __restrict__ trans,
    float* __restrict__ S) {
  __shared__ __align__(16) float cv[LL];
  __shared__ float pr[32][LL];
  __shared__ float l1[32][LL], l2[16][LL], l3[8][LL], l4[4][LL], l5[2][LL];
  compute_cvec(gpart, bp, cv, pr);

  const int wid = threadIdx.x >> 6, lane = threadIdx.x & 63;
  const int j = lane & 31, half = lane >> 5;
  const int b = blockIdx.x;                 // 0..255
  float4 tt[8];
  #pragma unroll
  for (int i = 0; i < 8; ++i) tt[i] = *(const float4*)(trans + j * LL + i * 4);
  const float cj = cv[j];
  float4 sv[8];

  // phase 1: width 8192 (nodes 16384+), children are leaves (add cv)
  #pragma unroll
  for (int k = wid; k < 32; k += 16) {
    const int n = b * 32 + k;
    const float* sp = E0 + (size_t)(2 * n + half) * LL;
    #pragma unroll
    for (int i = 0; i < 8; ++i) {
      float4 vv = *(const float4*)(sp + i * 4);
      float4 c4 = *(const float4*)(cv + i * 4);
      vv.x += c4.x; vv.y += c4.y; vv.z += c4.z; vv.w += c4.w;
      sv[i] = vv;
    }
    float lsum = lse32(tt, sv);
    float other = __shfl_xor(lsum, 32, 64);
    float o = E0[(size_t)(16384 + n) * LL + j] + cj + lsum + other;
    if (lane < 32) l1[k][j] = o;
  }
  __syncthreads();
  // phase 2: width 4096 (nodes 24576+)
  if (wid < 16) {
    const float* sp = l1[2 * wid + half];
    #pragma unroll
    for (int i = 0; i < 8; ++i) sv[i] = *(const float4*)(sp + i * 4);
    float lsum = lse32(tt, sv);
    float other = __shfl_xor(lsum, 32, 64);
    float o = E0[(size_t)(24576 + b * 16 + wid) * LL + j] + cj + lsum + other;
    if (lane < 32) l2[wid][j] = o;
  }
  __syncthreads();
  // phase 3: width 2048 (nodes 28672+)
  if (wid < 8) {
    const float* sp = l2[2 * wid + half];
    #pragma unroll
    for (int i = 0; i < 8; ++i) sv[i] = *(const float4*)(sp + i * 4);
    float lsum = lse32(tt, sv);
    float other = __shfl_xor(lsum, 32, 64);
    float o = E0[(size_t)(28672 + b * 8 + wid) * LL + j] + cj + lsum + other;
    if (lane < 32) l3[wid][j] = o;
  }
  __syncthreads();
  // phase 4: width 1024 (nodes 30720+)
  if (wid < 4) {
    const float* sp = l3[2 * wid + half];
    #pragma unroll
    for (int i = 0; i < 8; ++i) sv[i] = *(const float4*)(sp + i * 4);
    float lsum = lse32(tt, sv);
    float other = __shfl_xor(lsum, 32, 64);
    float o = E0[(size_t)(30720 + b * 4 + wid) * LL + j] + cj + lsum + other;
    if (lane < 32) l4[wid][j] = o;
  }
  __syncthreads();
  // phase 5: width 512 (nodes 31744+)
  if (wid < 2) {
    const float* sp = l4[2 * wid + half];
    #pragma unroll
    for (int i = 0; i < 8; ++i) sv[i] = *(const float4*)(sp + i * 4);
    float lsum = lse32(tt, sv);
    float other = __shfl_xor(lsum, 32, 64);
    float o = E0[(size_t)(31744 + b * 2 + wid) * LL + j] + cj + lsum + other;
    if (lane < 32) l5[wid][j] = o;
  }
  __syncthreads();
  // phase 6: width 256 (nodes 32256+)
  if (wid == 0) {
    const float* sp = l5[half];
    #pragma unroll
    for (int i = 0; i < 8; ++i) sv[i] = *(const float4*)(sp + i * 4);
    float lsum = lse32(tt, sv);
    float other = __shfl_xor(lsum, 32, 64);
    float o = E0[(size_t)(32256 + b) * LL + j] + cj + lsum + other;
    if (lane < 32) S[(size_t)b * LL + j] = o;
  }
}

// Widths 128..1 (nodes 32512..32766) in one block; first level's children are
// the width-256 nodes in S. Writes root scores to out.
__global__ __launch_bounds__(1024) void tail_kernel(
    const float* __restrict__ E0, const float* __restrict__ gpart,
    const float* __restrict__ bp, const float* __restrict__ trans,
    const float* __restrict__ S, float* __restrict__ out) {
  __shared__ __align__(16) float cv[LL];
  __shared__ float pr[32][LL];
  __shared__ float ts[255 * LL];            // nodes 32512..32766
  compute_cvec(gpart, bp, cv, pr);

  const int wid = threadIdx.x >> 6, lane = threadIdx.x & 63;
  const int j = lane & 31, half = lane >> 5;
  float4 tt[8];
  #pragma unroll
  for (int i = 0; i < 8; ++i) tt[i] = *(const float4*)(trans + j * LL + i * 4);
  const float cj = cv[j];
  float4 sv[8];

  int width = 128, pnode = 32512, cIdxBase = -1;
  while (width >= 1) {
    for (int n = wid; n < width; n += 16) {
      const float* sp = (cIdxBase < 0)
          ? (S + (size_t)(2 * n + half) * LL)
          : (ts + (size_t)(cIdxBase + 2 * n + half) * LL);
      #pragma unroll
      for (int i = 0; i < 8; ++i) sv[i] = *(const float4*)(sp + i * 4);
      float lsum = lse32(tt, sv);
      float other = __shfl_xor(lsum, 32, 64);
      if (lane < 32) {
        const int node = pnode + n;
        float o = E0[(size_t)node * LL + j] + cj + lsum + other;
        ts[(size_t)(node - 32512) * LL + j] = o;
        if (node == NN - 1) out[j] = o;
      }
    }
    __syncthreads();
    cIdxBase = pnode - 32512;
    pnode += width;
    width >>= 1;
  }
}

extern "C" void kernel_launch(void* const* d_in, const int* in_sizes, int n_in,
                              void* d_out, int out_size, void* d_ws, size_t ws_size,
                              hipStream_t stream) {
  const float* hidden = (const float*)d_in[0];
  const float* trans  = (const float*)d_in[1];
  const float* Wp     = (const float*)d_in[2];
  const float* bp     = (const float*)d_in[3];

  float* ws    = (float*)d_ws;
  float* E0    = ws;                               // NN*32 f32
  float* gpart = E0 + (size_t)NN * LL;             // 2048*32 f32
  float* S     = gpart + (size_t)2048 * LL;        // 256*32 f32
  short* Wpk   = (short*)(S + 256 * LL);           // 65536 bf16

  pack_kernel<<<64, 256, 0, stream>>>(Wp, Wpk);
  gemm_kernel<<<512, 256, 0, stream>>>(hidden, Wpk, E0, gpart);
  // widths 8192..256 -> S = width-256 node scores (nodes 32256..32511)
  treeA_kernel<<<256, 1024, 0, stream>>>(E0, gpart, bp, trans, S);
  // widths 128..1 + root write
  tail_kernel<<<1, 1024, 0, stream>>>(E0, gpart, bp, trans, S, (float*)d_out);
}